// Round 1
// baseline (22602.397 us; speedup 1.0000x reference)
//
#include <hip/hip_runtime.h>
#include <hip/hip_bf16.h>
#include <cstdint>
#include <cstddef>

// ---------------------------------------------------------------------------
// MultilayerGRU: emb-gather -> GRU(256->512) -> GRU(512->512) -> FC(512->128)
//                -> log_softmax
// B=32, S=512, DI=256, DH=512, DO=128, V=32000
//
// Strategy:
//  - batched bf16 MFMA GEMMs for all input projections (x_t @ W_x parts)
//  - persistent 64-WG kernel per layer for the recurrence; per-WG weight slice
//    resident in LDS; h broadcast via global; 2 device-scope barriers / step
// ---------------------------------------------------------------------------

typedef short v8ss __attribute__((ext_vector_type(8)));     // 8 bf16 (4 VGPR)
typedef float v4f  __attribute__((ext_vector_type(4)));
typedef unsigned short u16x4 __attribute__((ext_vector_type(4)));
typedef unsigned short u16x8 __attribute__((ext_vector_type(8)));

#define MFMA16(a, b, c) __builtin_amdgcn_mfma_f32_16x16x32_bf16((a), (b), (c), 0, 0, 0)

__device__ __forceinline__ unsigned short f2bf(float f) {
  union { float f; unsigned u; } v; v.f = f;
  unsigned r = v.u + 0x7fffu + ((v.u >> 16) & 1u);   // RNE
  return (unsigned short)(r >> 16);
}
__device__ __forceinline__ float bf2f(unsigned short h) {
  union { unsigned u; float f; } v; v.u = ((unsigned)h) << 16; return v.f;
}

// ----- sizes -----
#define BB   32
#define SS   512
#define DI   256
#define DH   512
#define DO   128
#define MROWS (BB * SS)          // 16384, row index = t*32 + b
#define NGATE (3 * DH)           // 1536
#define RNWG 64                  // WGs in recurrence kernel (own 8 cols each)

// ----- ws offsets (bytes) -----
#define O_CTRL   0               // cnt0@0 flag0@128 cnt1@256 flag1@384
#define O_HG0    1024
#define O_HG1    (O_HG0 + 32768)
#define O_RHG0   (O_HG1 + 32768)
#define O_RHG1   (O_RHG0 + 32768)
#define O_ZERO_END (O_RHG1 + 32768)          // 132096 : memset [0, here)
#define O_WT0X   O_ZERO_END                  // [1536][256] bf16
#define O_WT0H   (O_WT0X + 1536*256*2)       // [64][24][512] bf16
#define O_WT1X   (O_WT0H + RNWG*24*512*2)    // [1536][512] bf16
#define O_WT1H   (O_WT1X + 1536*512*2)       // [64][24][512] bf16
#define O_WTFC   (O_WT1H + RNWG*24*512*2)    // [128][512] bf16
#define O_XEMB   (O_WTFC + 128*512*2)        // [16384][256] bf16
#define O_Y0     (O_XEMB + (size_t)MROWS*DI*2)   // [16384][512] bf16
#define O_Y1     (O_Y0   + (size_t)MROWS*DH*2)
#define O_LOGITS (O_Y1   + (size_t)MROWS*DH*2)   // [16384][128] f32
#define O_XP     (O_LOGITS + (size_t)MROWS*DO*4) // [512][1536][32] bf16

// ---------------------------------------------------------------------------
// weight repack: f32 -> bf16 in GEMM-friendly transposed layouts
// ---------------------------------------------------------------------------
__global__ void prep_kernel(const float* __restrict__ l0Wz, const float* __restrict__ l0Wr,
                            const float* __restrict__ l0Wn,
                            const float* __restrict__ l1Wz, const float* __restrict__ l1Wr,
                            const float* __restrict__ l1Wn,
                            const float* __restrict__ fcW,
                            unsigned short* __restrict__ Wt0x, unsigned short* __restrict__ Wt0h,
                            unsigned short* __restrict__ Wt1x, unsigned short* __restrict__ Wt1h,
                            unsigned short* __restrict__ WtFC) {
  const int n0 = 1536 * 256;        // Wt0x
  const int n1 = RNWG * 24 * 512;   // Wt0h
  const int n2 = 1536 * 512;        // Wt1x
  const int n3 = RNWG * 24 * 512;   // Wt1h
  const int n4 = 128 * 512;         // WtFC
  const int total = n0 + n1 + n2 + n3 + n4;
  for (int i = blockIdx.x * 256 + threadIdx.x; i < total; i += gridDim.x * 256) {
    int j = i;
    if (j < n0) {  // Wt0x[gcol][k] = l0_W{g}[k][c]
      int gcol = j / 256, k = j % 256, g = gcol >> 9, c = gcol & 511;
      const float* W = g == 0 ? l0Wz : (g == 1 ? l0Wr : l0Wn);
      Wt0x[j] = f2bf(W[k * 512 + c]); continue;
    }
    j -= n0;
    if (j < n1) {  // Wt0h[wg][lr][k] = l0_W{g(lr)}[256+k][wg*8+(lr&7)]
      int wg = j / (24 * 512), rem = j % (24 * 512), lr = rem / 512, k = rem % 512;
      int g = lr >> 3, c = (wg << 3) + (lr & 7);
      const float* W = g == 0 ? l0Wz : (g == 1 ? l0Wr : l0Wn);
      Wt0h[j] = f2bf(W[(256 + k) * 512 + c]); continue;
    }
    j -= n1;
    if (j < n2) {  // Wt1x[gcol][k] = l1_W{g}[k][c]
      int gcol = j / 512, k = j % 512, g = gcol >> 9, c = gcol & 511;
      const float* W = g == 0 ? l1Wz : (g == 1 ? l1Wr : l1Wn);
      Wt1x[j] = f2bf(W[k * 512 + c]); continue;
    }
    j -= n2;
    if (j < n3) {  // Wt1h[wg][lr][k] = l1_W{g(lr)}[512+k][wg*8+(lr&7)]
      int wg = j / (24 * 512), rem = j % (24 * 512), lr = rem / 512, k = rem % 512;
      int g = lr >> 3, c = (wg << 3) + (lr & 7);
      const float* W = g == 0 ? l1Wz : (g == 1 ? l1Wr : l1Wn);
      Wt1h[j] = f2bf(W[(512 + k) * 512 + c]); continue;
    }
    j -= n3;
    { int c = j / 512, k = j % 512; WtFC[j] = f2bf(fcW[k * 128 + c]); }
  }
}

// ---------------------------------------------------------------------------
// embedding gather: Xemb[(t*32+b)][k] = bf16(emb[tokens[b][t]][k])
// ---------------------------------------------------------------------------
__global__ void embed_kernel(const int* __restrict__ tokens, const float* __restrict__ emb,
                             unsigned short* __restrict__ Xemb) {
  int r = blockIdx.x;            // 0..16383  (t-major)
  int c = threadIdx.x;           // 0..255
  int t = r >> 5, b = r & 31;
  int tok = tokens[b * SS + t];
  Xemb[(size_t)r * DI + c] = f2bf(emb[(size_t)tok * DI + c]);
}

// ---------------------------------------------------------------------------
// batched input projection: Xp[t][gcol][b] = (A @ Bt^T)  (A:[16384][K], Bt:[1536][K])
// grid (512, 12), 256 threads (4 waves, each a 32x32 output tile)
// ---------------------------------------------------------------------------
template <int K>
__global__ __launch_bounds__(256) void xproj_kernel(const unsigned short* __restrict__ A,
                                                    const unsigned short* __restrict__ Bt,
                                                    unsigned short* __restrict__ Xp) {
  int w = threadIdx.x >> 6, l = threadIdx.x & 63;
  int cl = l & 15, kg = l >> 4;
  int m0 = blockIdx.x * 32;
  int n0 = blockIdx.y * 128 + w * 32;
  v4f acc[2][2] = {};
#pragma unroll
  for (int kc = 0; kc < K / 32; ++kc) {
    int ko = kc * 32 + kg * 8;
    v8ss a0 = *(const v8ss*)&A[(size_t)(m0 + cl) * K + ko];
    v8ss a1 = *(const v8ss*)&A[(size_t)(m0 + 16 + cl) * K + ko];
    v8ss b0 = *(const v8ss*)&Bt[(size_t)(n0 + cl) * K + ko];
    v8ss b1 = *(const v8ss*)&Bt[(size_t)(n0 + 16 + cl) * K + ko];
    acc[0][0] = MFMA16(a0, b0, acc[0][0]);
    acc[0][1] = MFMA16(a0, b1, acc[0][1]);
    acc[1][0] = MFMA16(a1, b0, acc[1][0]);
    acc[1][1] = MFMA16(a1, b1, acc[1][1]);
  }
  int t = blockIdx.x;   // m0 = t*32 exactly
#pragma unroll
  for (int mi = 0; mi < 2; ++mi)
#pragma unroll
    for (int ni = 0; ni < 2; ++ni) {
      int col = n0 + ni * 16 + cl;
      int bb0 = mi * 16 + kg * 4;
      u16x4 o;
      o[0] = f2bf(acc[mi][ni][0]); o[1] = f2bf(acc[mi][ni][1]);
      o[2] = f2bf(acc[mi][ni][2]); o[3] = f2bf(acc[mi][ni][3]);
      *(u16x4*)&Xp[((size_t)t * NGATE + col) * 32 + bb0] = o;
    }
}

// ---------------------------------------------------------------------------
// device-scope barrier across RNWG workgroups (epoch/target based)
// ---------------------------------------------------------------------------
__device__ __forceinline__ void gbar(unsigned* cnt, unsigned* flag, unsigned target) {
  __threadfence();
  __syncthreads();
  if (threadIdx.x == 0) {
    unsigned v = __hip_atomic_fetch_add(cnt, 1u, __ATOMIC_RELAXED, __HIP_MEMORY_SCOPE_AGENT);
    if (v == target * (unsigned)RNWG - 1u) {
      __hip_atomic_store(flag, target, __ATOMIC_RELEASE, __HIP_MEMORY_SCOPE_AGENT);
    } else {
      while (__hip_atomic_load(flag, __ATOMIC_RELAXED, __HIP_MEMORY_SCOPE_AGENT) < target)
        __builtin_amdgcn_s_sleep(2);
    }
  }
  __syncthreads();
  __threadfence();
}

// ---------------------------------------------------------------------------
// persistent GRU recurrence (one layer).  64 WGs x 256 thr; WG owns 8 H-cols.
// LDS: Wt [24][520] (Z8|R8|N8 recurrent weight cols), At [32][520] (h bcast),
//      zbuf/hbuf [32][8] f32.
// step: phaseA (waves 0,1): Z|R 16-col tile; publish Rg*h (own cols)
//       barrier; phaseB (waves 2,3): N tile (8 real cols); h' = (1-z)h + z*ht
//       publish h' bf16; barrier.
// ---------------------------------------------------------------------------
__global__ __launch_bounds__(256) void gru_rec_kernel(
    const unsigned short* __restrict__ WtH,  // [64][24][512]
    const unsigned short* __restrict__ Xp,   // [512][1536][32]
    unsigned short* __restrict__ Y,          // [16384][512]
    unsigned short* __restrict__ Hg,         // [32][512]  (zeroed before launch)
    unsigned short* __restrict__ RHg,        // [32][512]
    const float* __restrict__ bz, const float* __restrict__ br, const float* __restrict__ bn,
    unsigned* cnt, unsigned* flag) {
  __shared__ unsigned short Wt[24 * 520 + 8];
  __shared__ unsigned short At[32 * 520];
  __shared__ float zbuf[32 * 8];
  __shared__ float hbuf[32 * 8];

  const int tid = threadIdx.x;
  const int wg = blockIdx.x;
  const int w = tid >> 6, l = tid & 63, cl = l & 15, kg = l >> 4;

  // load recurrent weight slice into LDS (24 rows x 512 bf16)
  for (int ch = tid; ch < 24 * 64; ch += 256) {
    int lr = ch >> 6, off = (ch & 63) * 8;
    *(u16x8*)&Wt[lr * 520 + off] = *(const u16x8*)&WtH[((size_t)wg * 24 + lr) * 512 + off];
  }
  hbuf[tid] = 0.f;  // 256 == 32*8
  __syncthreads();

  for (int t = 0; t < SS; ++t) {
    // ---- stage h broadcast: Hg -> At ----
    for (int ch = tid; ch < 32 * 64; ch += 256) {
      int rr = ch >> 6, off = (ch & 63) * 8;
      *(u16x8*)&At[rr * 520 + off] = *(const u16x8*)&Hg[rr * 512 + off];
    }
    __syncthreads();

    // ---- phase A: Z (cols 0-7 of tile) | R (cols 8-15) ----
    if (w < 2) {
      const int mh = w;
      const int g = cl >> 3, c7 = cl & 7;
      const int gcol = g * 512 + wg * 8 + c7;
      const int b0 = mh * 16 + kg * 4;
      u16x4 xp4 = *(const u16x4*)&Xp[((size_t)t * NGATE + gcol) * 32 + b0];
      const float bias = (g ? br : bz)[wg * 8 + c7];
      v4f acc = {};
#pragma unroll
      for (int kc = 0; kc < 16; ++kc) {
        int ko = kc * 32 + kg * 8;
        v8ss af = *(const v8ss*)&At[(mh * 16 + cl) * 520 + ko];
        v8ss bf = *(const v8ss*)&Wt[cl * 520 + ko];
        acc = MFMA16(af, bf, acc);
      }
#pragma unroll
      for (int r = 0; r < 4; ++r) {
        int b = b0 + r;
        float pre = acc[r] + bf2f(xp4[r]) + bias;
        float gate = 1.f / (1.f + __expf(-pre));
        if (g == 0) {
          zbuf[b * 8 + c7] = gate;
        } else {
          float h = bf2f(At[b * 520 + wg * 8 + c7]);
          RHg[b * 512 + wg * 8 + c7] = f2bf(gate * h);
        }
      }
    }
    gbar(cnt, flag, 2u * t + 1u);

    // ---- phase B: N gate + state update (own 8 cols) ----
    if (w >= 2) {
      const int mh = w - 2;
      const int c7 = cl & 7;
      const int b0 = mh * 16 + kg * 4;
      const int gcol = 2 * 512 + wg * 8 + c7;
      u16x4 xp4 = *(const u16x4*)&Xp[((size_t)t * NGATE + gcol) * 32 + b0];
      const float bias = bn[wg * 8 + c7];
      v4f acc = {};
#pragma unroll
      for (int kc = 0; kc < 16; ++kc) {
        int ko = kc * 32 + kg * 8;
        v8ss af = *(const v8ss*)&RHg[(size_t)(mh * 16 + cl) * 512 + ko];  // global
        v8ss bf = *(const v8ss*)&Wt[(16 + c7) * 520 + ko];  // lanes 8-15 dup cols
        acc = MFMA16(af, bf, acc);
      }
      if (cl < 8) {
#pragma unroll
        for (int r = 0; r < 4; ++r) {
          int b = b0 + r;
          float pre = acc[r] + bf2f(xp4[r]) + bias;
          float ht = tanhf(pre);
          float z = zbuf[b * 8 + cl];
          float hn = (1.f - z) * hbuf[b * 8 + cl] + z * ht;
          hbuf[b * 8 + cl] = hn;
          unsigned short hb = f2bf(hn);
          Hg[b * 512 + wg * 8 + cl] = hb;
          Y[((size_t)(t * 32 + b)) * 512 + wg * 8 + cl] = hb;
        }
      }
    }
    gbar(cnt, flag, 2u * t + 2u);
  }
}

// ---------------------------------------------------------------------------
// FC: logits[m][c] = Y1[m][:] @ fc_W[:][c] + fc_b[c]   (M=16384, N=128, K=512)
// ---------------------------------------------------------------------------
__global__ __launch_bounds__(256) void fc_kernel(const unsigned short* __restrict__ Y1,
                                                 const unsigned short* __restrict__ WtFC,
                                                 const float* __restrict__ fcb,
                                                 float* __restrict__ logits) {
  int w = threadIdx.x >> 6, l = threadIdx.x & 63;
  int cl = l & 15, kg = l >> 4;
  int m0 = blockIdx.x * 32, n0 = w * 32;
  v4f acc[2][2] = {};
#pragma unroll
  for (int kc = 0; kc < 16; ++kc) {
    int ko = kc * 32 + kg * 8;
    v8ss a0 = *(const v8ss*)&Y1[(size_t)(m0 + cl) * 512 + ko];
    v8ss a1 = *(const v8ss*)&Y1[(size_t)(m0 + 16 + cl) * 512 + ko];
    v8ss b0 = *(const v8ss*)&WtFC[(size_t)(n0 + cl) * 512 + ko];
    v8ss b1 = *(const v8ss*)&WtFC[(size_t)(n0 + 16 + cl) * 512 + ko];
    acc[0][0] = MFMA16(a0, b0, acc[0][0]);
    acc[0][1] = MFMA16(a0, b1, acc[0][1]);
    acc[1][0] = MFMA16(a1, b0, acc[1][0]);
    acc[1][1] = MFMA16(a1, b1, acc[1][1]);
  }
#pragma unroll
  for (int mi = 0; mi < 2; ++mi)
#pragma unroll
    for (int ni = 0; ni < 2; ++ni) {
      int col = n0 + ni * 16 + cl;
      float bias = fcb[col];
#pragma unroll
      for (int r = 0; r < 4; ++r) {
        int m = m0 + mi * 16 + kg * 4 + r;
        logits[(size_t)m * 128 + col] = acc[mi][ni][r] + bias;
      }
    }
}

// ---------------------------------------------------------------------------
// row-wise log_softmax over 128 cols; remap rows t-major -> out [B][S][128]
// ---------------------------------------------------------------------------
__global__ void lsm_kernel(const float* __restrict__ logits, float* __restrict__ out) {
  int w = threadIdx.x >> 6, l = threadIdx.x & 63;
  int row = blockIdx.x * 4 + w;  // 0..16383
  const float* x = &logits[(size_t)row * 128];
  float a = x[l], b2 = x[l + 64];
  float m = fmaxf(a, b2);
#pragma unroll
  for (int off = 32; off; off >>= 1) m = fmaxf(m, __shfl_xor(m, off));
  float s = __expf(a - m) + __expf(b2 - m);
#pragma unroll
  for (int off = 32; off; off >>= 1) s += __shfl_xor(s, off);
  float lse = m + logf(s);
  int t = row >> 5, bb = row & 31;
  float* o = &out[((size_t)bb * SS + t) * 128];
  o[l] = a - lse;
  o[l + 64] = b2 - lse;
}

// ---------------------------------------------------------------------------
extern "C" void kernel_launch(void* const* d_in, const int* in_sizes, int n_in,
                              void* d_out, int out_size, void* d_ws, size_t ws_size,
                              hipStream_t stream) {
  (void)in_sizes; (void)n_in; (void)out_size; (void)ws_size;
  const int*   tokens = (const int*)d_in[0];
  const float* emb    = (const float*)d_in[1];
  const float* l0Wz = (const float*)d_in[2];  const float* l0bz = (const float*)d_in[3];
  const float* l0Wr = (const float*)d_in[4];  const float* l0br = (const float*)d_in[5];
  const float* l0Wn = (const float*)d_in[6];  const float* l0bn = (const float*)d_in[7];
  const float* l1Wz = (const float*)d_in[8];  const float* l1bz = (const float*)d_in[9];
  const float* l1Wr = (const float*)d_in[10]; const float* l1br = (const float*)d_in[11];
  const float* l1Wn = (const float*)d_in[12]; const float* l1bn = (const float*)d_in[13];
  const float* fcW  = (const float*)d_in[14]; const float* fcb  = (const float*)d_in[15];

  char* ws = (char*)d_ws;
  unsigned* cnt0  = (unsigned*)(ws + O_CTRL);
  unsigned* flag0 = (unsigned*)(ws + O_CTRL + 128);
  unsigned* cnt1  = (unsigned*)(ws + O_CTRL + 256);
  unsigned* flag1 = (unsigned*)(ws + O_CTRL + 384);
  unsigned short* Hg0  = (unsigned short*)(ws + O_HG0);
  unsigned short* Hg1  = (unsigned short*)(ws + O_HG1);
  unsigned short* RHg0 = (unsigned short*)(ws + O_RHG0);
  unsigned short* RHg1 = (unsigned short*)(ws + O_RHG1);
  unsigned short* Wt0x = (unsigned short*)(ws + O_WT0X);
  unsigned short* Wt0h = (unsigned short*)(ws + O_WT0H);
  unsigned short* Wt1x = (unsigned short*)(ws + O_WT1X);
  unsigned short* Wt1h = (unsigned short*)(ws + O_WT1H);
  unsigned short* WtFC = (unsigned short*)(ws + O_WTFC);
  unsigned short* Xemb = (unsigned short*)(ws + O_XEMB);
  unsigned short* Y0   = (unsigned short*)(ws + O_Y0);
  unsigned short* Y1   = (unsigned short*)(ws + O_Y1);
  float*          logits = (float*)(ws + O_LOGITS);
  unsigned short* Xp   = (unsigned short*)(ws + O_XP);

  // zero barrier counters + H state (graph-capture-safe async memset)
  hipMemsetAsync(ws, 0, O_ZERO_END, stream);

  prep_kernel<<<4096, 256, 0, stream>>>(l0Wz, l0Wr, l0Wn, l1Wz, l1Wr, l1Wn, fcW,
                                        Wt0x, Wt0h, Wt1x, Wt1h, WtFC);
  embed_kernel<<<MROWS, 256, 0, stream>>>(tokens, emb, Xemb);

  // layer 0: input projections (K=256), then recurrence
  xproj_kernel<256><<<dim3(512, 12), 256, 0, stream>>>(Xemb, Wt0x, Xp);
  gru_rec_kernel<<<RNWG, 256, 0, stream>>>(Wt0h, Xp, Y0, Hg0, RHg0, l0bz, l0br, l0bn,
                                           cnt0, flag0);
  // layer 1: input projections from Y0 (K=512), then recurrence
  xproj_kernel<512><<<dim3(512, 12), 256, 0, stream>>>(Y0, Wt1x, Xp);
  gru_rec_kernel<<<RNWG, 256, 0, stream>>>(Wt1h, Xp, Y1, Hg1, RHg1, l1bz, l1br, l1bn,
                                           cnt1, flag1);

  fc_kernel<<<512, 256, 0, stream>>>(Y1, WtFC, fcb, logits);
  lsm_kernel<<<4096, 256, 0, stream>>>(logits, (float*)d_out);
}

// Round 4
// 6598.151 us; speedup vs baseline: 3.4256x; 3.4256x over previous
//
#include <hip/hip_runtime.h>
#include <hip/hip_bf16.h>
#include <cstdint>
#include <cstddef>

// ---------------------------------------------------------------------------
// MultilayerGRU: emb-gather -> GRU(256->512) -> GRU(512->512) -> FC(512->128)
//                -> log_softmax.   B=32, S=512, DI=256, DH=512, DO=128
//
// Round-4: XCD-local recurrence groups; ALL cross-WG reads are inline-asm
// global_atomic_add (sc0, add-0) -- a real TCC RMW that InstCombine cannot
// turn into an L1-served load (the r2/r3 livelock). Sticky per-group abort
// guarantees fast failure instead of a 600 s hang.
// ---------------------------------------------------------------------------

typedef short v8ss __attribute__((ext_vector_type(8)));     // 8 bf16 (4 VGPR)
typedef float v4f  __attribute__((ext_vector_type(4)));
typedef unsigned short u16x4 __attribute__((ext_vector_type(4)));
typedef unsigned short u16x8 __attribute__((ext_vector_type(8)));
typedef unsigned long long u64;

#define MFMA16(a, b, c) __builtin_amdgcn_mfma_f32_16x16x32_bf16((a), (b), (c), 0, 0, 0)

__device__ __forceinline__ unsigned short f2bf(float f) {
  union { float f; unsigned u; } v; v.f = f;
  unsigned r = v.u + 0x7fffu + ((v.u >> 16) & 1u);   // RNE
  return (unsigned short)(r >> 16);
}
__device__ __forceinline__ float bf2f(unsigned short h) {
  union { unsigned u; float f; } v; v.u = ((unsigned)h) << 16; return v.f;
}

// Real TCC-executed 32-bit atomic add returning old value (sc0 = return-old).
// Leading waitcnt: all of THIS wave's prior stores are in L2 before the RMW.
__device__ __forceinline__ unsigned gatom32(unsigned* p, unsigned v) {
  unsigned out;
  asm volatile("s_waitcnt vmcnt(0)\n\t"
               "global_atomic_add %0, %1, %2, off sc0\n\t"
               "s_waitcnt vmcnt(0)"
               : "=&v"(out) : "v"(p), "v"(v) : "memory");
  return out;
}
// Two overlapped 8B atomic reads (add 0) -> 16 fresh bytes from local L2.
__device__ __forceinline__ void gatom64x2(u64* p, u64& a, u64& b) {
  u64 va, vb; u64 zero = 0;
  asm volatile("global_atomic_add_x2 %0, %2, %4, off sc0\n\t"
               "global_atomic_add_x2 %1, %3, %4, off sc0\n\t"
               "s_waitcnt vmcnt(0)"
               : "=&v"(va), "=&v"(vb)
               : "v"(p), "v"(p + 1), "v"(zero)
               : "memory");
  a = va; b = vb;
}

// ----- sizes -----
#define BB   32
#define SS   512
#define DI   256
#define DH   512
#define DO   128
#define MROWS (BB * SS)          // 16384, row index = t*32 + b
#define NGATE (3 * DH)           // 1536
#define WPG  16                  // worker WGs per group
#define BPG  4                   // batches per group

// ----- ws offsets (bytes) -----
#define O_CLM0   0               // claim counters, layer 0: [8] @ g*128B
#define O_CLM1   1024
#define O_CNT0   2048            // barrier counters
#define O_CNT1   3072
#define O_ABT0   4096            // per-group abort cells
#define O_ABT1   5120
#define O_HX0    6144            // [8][4][512] bf16
#define O_RHX0   (O_HX0 + 32768)
#define O_HX1    (O_RHX0 + 32768)
#define O_RHX1   (O_HX1 + 32768)
#define O_ZERO_END (O_RHX1 + 32768)          // 137216 : memset [0, here) every call
#define O_WT0X   O_ZERO_END                  // [1536][256] bf16
#define O_WT0H   (O_WT0X + 1536*256*2)       // [16][96][512] bf16
#define O_WT1X   (O_WT0H + 16*96*512*2)      // [1536][512] bf16
#define O_WT1H   (O_WT1X + 1536*512*2)       // [16][96][512] bf16
#define O_WTFC   (O_WT1H + 16*96*512*2)      // [128][512] bf16
#define O_XEMB   (O_WTFC + 128*512*2)        // [16384][256] bf16
#define O_Y0     (O_XEMB + (size_t)MROWS*DI*2)   // [16384][512] bf16
#define O_Y1     (O_Y0   + (size_t)MROWS*DH*2)
#define O_LOGITS (O_Y1   + (size_t)MROWS*DH*2)   // [16384][128] f32
#define O_XP     (O_LOGITS + (size_t)MROWS*DO*4) // [512][1536][32] bf16

// ---------------------------------------------------------------------------
// weight repack: f32 -> bf16 transposed layouts
// ---------------------------------------------------------------------------
__global__ void prep_kernel(const float* __restrict__ l0Wz, const float* __restrict__ l0Wr,
                            const float* __restrict__ l0Wn,
                            const float* __restrict__ l1Wz, const float* __restrict__ l1Wr,
                            const float* __restrict__ l1Wn,
                            const float* __restrict__ fcW,
                            unsigned short* __restrict__ Wt0x, unsigned short* __restrict__ Wt0h,
                            unsigned short* __restrict__ Wt1x, unsigned short* __restrict__ Wt1h,
                            unsigned short* __restrict__ WtFC) {
  const int n0 = 1536 * 256;        // Wt0x
  const int n1 = 16 * 96 * 512;     // Wt0h
  const int n2 = 1536 * 512;        // Wt1x
  const int n3 = 16 * 96 * 512;     // Wt1h
  const int n4 = 128 * 512;         // WtFC
  const int total = n0 + n1 + n2 + n3 + n4;
  for (int i = blockIdx.x * 256 + threadIdx.x; i < total; i += gridDim.x * 256) {
    int j = i;
    if (j < n0) {  // Wt0x[gcol][k] = l0_W{g}[k][c]
      int gcol = j / 256, k = j % 256, g = gcol >> 9, c = gcol & 511;
      const float* W = g == 0 ? l0Wz : (g == 1 ? l0Wr : l0Wn);
      Wt0x[j] = f2bf(W[k * 512 + c]); continue;
    }
    j -= n0;
    if (j < n1) {  // Wt0h[r][row][k] = l0_W{g(row)}[256+k][r*32 + (row&31)]
      int r = j / (96 * 512), rem = j % (96 * 512), row = rem / 512, k = rem % 512;
      int g = row >> 5, c = r * 32 + (row & 31);
      const float* W = g == 0 ? l0Wz : (g == 1 ? l0Wr : l0Wn);
      Wt0h[j] = f2bf(W[(256 + k) * 512 + c]); continue;
    }
    j -= n1;
    if (j < n2) {  // Wt1x[gcol][k] = l1_W{g}[k][c]
      int gcol = j / 512, k = j % 512, g = gcol >> 9, c = gcol & 511;
      const float* W = g == 0 ? l1Wz : (g == 1 ? l1Wr : l1Wn);
      Wt1x[j] = f2bf(W[k * 512 + c]); continue;
    }
    j -= n2;
    if (j < n3) {  // Wt1h[r][row][k] = l1_W{g(row)}[512+k][r*32 + (row&31)]
      int r = j / (96 * 512), rem = j % (96 * 512), row = rem / 512, k = rem % 512;
      int g = row >> 5, c = r * 32 + (row & 31);
      const float* W = g == 0 ? l1Wz : (g == 1 ? l1Wr : l1Wn);
      Wt1h[j] = f2bf(W[(512 + k) * 512 + c]); continue;
    }
    j -= n3;
    { int c = j / 512, k = j % 512; WtFC[j] = f2bf(fcW[k * 128 + c]); }
  }
}

// ---------------------------------------------------------------------------
// embedding gather
// ---------------------------------------------------------------------------
__global__ void embed_kernel(const int* __restrict__ tokens, const float* __restrict__ emb,
                             unsigned short* __restrict__ Xemb) {
  int r = blockIdx.x;            // 0..16383  (t-major)
  int c = threadIdx.x;           // 0..255
  int t = r >> 5, b = r & 31;
  int tok = tokens[b * SS + t];
  Xemb[(size_t)r * DI + c] = f2bf(emb[(size_t)tok * DI + c]);
}

// ---------------------------------------------------------------------------
// batched input projection: Xp[t][gcol][b]  (A:[16384][K], Bt:[1536][K])
// ---------------------------------------------------------------------------
template <int K>
__global__ __launch_bounds__(256) void xproj_kernel(const unsigned short* __restrict__ A,
                                                    const unsigned short* __restrict__ Bt,
                                                    unsigned short* __restrict__ Xp) {
  int w = threadIdx.x >> 6, l = threadIdx.x & 63;
  int cl = l & 15, kg = l >> 4;
  int m0 = blockIdx.x * 32;
  int n0 = blockIdx.y * 128 + w * 32;
  v4f acc[2][2] = {};
#pragma unroll
  for (int kc = 0; kc < K / 32; ++kc) {
    int ko = kc * 32 + kg * 8;
    v8ss a0 = *(const v8ss*)&A[(size_t)(m0 + cl) * K + ko];
    v8ss a1 = *(const v8ss*)&A[(size_t)(m0 + 16 + cl) * K + ko];
    v8ss b0 = *(const v8ss*)&Bt[(size_t)(n0 + cl) * K + ko];
    v8ss b1 = *(const v8ss*)&Bt[(size_t)(n0 + 16 + cl) * K + ko];
    acc[0][0] = MFMA16(a0, b0, acc[0][0]);
    acc[0][1] = MFMA16(a0, b1, acc[0][1]);
    acc[1][0] = MFMA16(a1, b0, acc[1][0]);
    acc[1][1] = MFMA16(a1, b1, acc[1][1]);
  }
  int t = blockIdx.x;
#pragma unroll
  for (int mi = 0; mi < 2; ++mi)
#pragma unroll
    for (int ni = 0; ni < 2; ++ni) {
      int col = n0 + ni * 16 + cl;
      int bb0 = mi * 16 + kg * 4;
      u16x4 o;
      o[0] = f2bf(acc[mi][ni][0]); o[1] = f2bf(acc[mi][ni][1]);
      o[2] = f2bf(acc[mi][ni][2]); o[3] = f2bf(acc[mi][ni][3]);
      *(u16x4*)&Xp[((size_t)t * NGATE + col) * 32 + bb0] = o;
    }
}

// ---------------------------------------------------------------------------
// persistent GRU recurrence, XCD-local groups; see round-4 header.
// ---------------------------------------------------------------------------
__global__ __launch_bounds__(256) void gru_rec2(
    const unsigned short* __restrict__ WtH,  // [16][96][512]
    const unsigned short* __restrict__ Xp,   // [512][1536][32]
    unsigned short* __restrict__ Y,          // [16384][512]
    unsigned short* hx,                       // [8][4][512] bf16 (zeroed)
    unsigned short* rhx,                      // [8][4][512] bf16 (zeroed)
    const float* __restrict__ bz, const float* __restrict__ br, const float* __restrict__ bn,
    unsigned* claim, unsigned* cnt, unsigned* abt) {   // [8] @ g*32, all zeroed
  __shared__ unsigned short Wt[96 * 520];
  __shared__ unsigned short At[16 * 520];
  __shared__ unsigned short Rt[16 * 520];
  __shared__ float zbuf[4 * 32];
  __shared__ float hbuf[4 * 32];
  __shared__ int role_sh, xcc_sh, dead;

  const int tid = threadIdx.x;
  if (tid == 0) {
    unsigned xcc;
    asm volatile("s_getreg_b32 %0, hwreg(HW_REG_XCC_ID)" : "=s"(xcc));
    xcc &= 7u;
    unsigned r = gatom32(&claim[xcc * 32], 1u);
    role_sh = (int)r; xcc_sh = (int)xcc; dead = 0;
  }
  __syncthreads();
  const int role = role_sh, g = xcc_sh;
  if (role >= WPG) return;   // spare WG

  // load this role's recurrent-weight slice into LDS (96 rows x 512)
  for (int ch = tid; ch < 96 * 64; ch += 256) {
    int row = ch >> 6, off = (ch & 63) * 8;
    *(u16x8*)&Wt[row * 520 + off] = *(const u16x8*)&WtH[((size_t)role * 96 + row) * 512 + off];
  }
  // zero At/Rt (rows 4-15 stay zero = MFMA row padding) and z/h state
  for (int i = tid * 8; i < 16 * 520; i += 256 * 8) {
    *(u16x8*)&At[i] = (u16x8)0;
    *(u16x8*)&Rt[i] = (u16x8)0;
  }
  if (tid < 128) { zbuf[tid] = 0.f; hbuf[tid] = 0.f; }
  __syncthreads();

  unsigned short* hxg  = hx  + (size_t)g * (BPG * 512);
  unsigned short* rhxg = rhx + (size_t)g * (BPG * 512);
  unsigned* cntg = &cnt[g * 32];
  unsigned* abtg = &abt[g * 32];

  const int w = tid >> 6, l = tid & 63, cl = l & 15, kg = l >> 4;
  const int gate = w >> 1;             // phase A: 0=Z (waves 0,1), 1=R (waves 2,3)
  const int lc16 = (w & 1) * 16;
  const int colA = role * 32 + lc16 + cl;       // phase-A column (global H index)
  const float biasA = (gate ? br : bz)[colA];
  const int lc16b = (w & 1) * 16;                // phase-B tile (waves 0,1 only)
  const int colB = role * 32 + lc16b + cl;
  const float biasB = (w < 2) ? bn[colB] : 0.f;

  // LDS dst for stage loads: row = tid>>6 (0..3), 16B chunk = tid&63
  u64* atdst = (u64*)&At[(tid >> 6) * 520 + (tid & 63) * 8];
  u64* rtdst = (u64*)&Rt[(tid >> 6) * 520 + (tid & 63) * 8];
  u64* hxsrc  = (u64*)hxg  + tid * 2;
  u64* rhxsrc = (u64*)rhxg + tid * 2;

  for (int t = 0; t < SS; ++t) {
    // ---- stage h: TCC atomic reads -> LDS At ----
    { u64 v0, v1; gatom64x2(hxsrc, v0, v1); atdst[0] = v0; atdst[1] = v1; }
    __syncthreads();

    // ---- phase A: Z | R, 16 cols per wave ----
    {
      u16x4 xp4 = *(const u16x4*)&Xp[((size_t)t * NGATE + gate * 512 + colA) * 32 + 4 * g];
      v4f acc = {};
#pragma unroll
      for (int kc = 0; kc < 16; ++kc) {
        int ko = kc * 32 + kg * 8;
        v8ss a = *(const v8ss*)&At[cl * 520 + ko];
        v8ss b = *(const v8ss*)&Wt[(gate * 32 + lc16 + cl) * 520 + ko];
        acc = MFMA16(a, b, acc);
      }
      if (l < 16) {   // lanes 0-15 hold rows 0-3 (= the 4 real batches)
        int lc = lc16 + cl;
#pragma unroll
        for (int j = 0; j < BPG; ++j) {
          float pre = acc[j] + bf2f(xp4[j]) + biasA;
          float gv = 1.f / (1.f + __expf(-pre));
          if (gate == 0) {
            zbuf[j * 32 + lc] = gv;
          } else {
            rhxg[j * 512 + colA] = f2bf(gv * hbuf[j * 32 + lc]);
          }
        }
      }
    }
    // ---- barrier A (syncthreads drains every wave's stores first) ----
    __syncthreads();
    if (tid == 0 && !dead) {
      gatom32(cntg, 1u);
      unsigned tgt = 32u * (unsigned)t + 16u;
      for (int it = 0;; ++it) {
        unsigned v = gatom32(cntg, 0u);
        if ((int)(v - tgt) >= 0) break;
        if (gatom32(abtg, 0u) != 0u) { dead = 1; break; }
        if (it >= (1 << 18)) { gatom32(abtg, 1u); dead = 1; break; }
        __builtin_amdgcn_s_sleep(2);
      }
    }
    __syncthreads();
    if (dead) break;

    // ---- stage rh: TCC atomic reads -> LDS Rt ----
    { u64 v0, v1; gatom64x2(rhxsrc, v0, v1); rtdst[0] = v0; rtdst[1] = v1; }
    __syncthreads();

    // ---- phase B: N gate + state update (waves 0,1) ----
    if (w < 2) {
      u16x4 xpn = *(const u16x4*)&Xp[((size_t)t * NGATE + 1024 + colB) * 32 + 4 * g];
      v4f acc = {};
#pragma unroll
      for (int kc = 0; kc < 16; ++kc) {
        int ko = kc * 32 + kg * 8;
        v8ss a = *(const v8ss*)&Rt[cl * 520 + ko];
        v8ss b = *(const v8ss*)&Wt[(64 + lc16b + cl) * 520 + ko];
        acc = MFMA16(a, b, acc);
      }
      if (l < 16) {
        int lc = lc16b + cl;
#pragma unroll
        for (int j = 0; j < BPG; ++j) {
          float pre = acc[j] + bf2f(xpn[j]) + biasB;
          float ht = 1.f - 2.f / (__expf(2.f * pre) + 1.f);   // overflow-safe tanh
          float z = zbuf[j * 32 + lc];
          float hn = (1.f - z) * hbuf[j * 32 + lc] + z * ht;
          hbuf[j * 32 + lc] = hn;
          unsigned short hb = f2bf(hn);
          hxg[j * 512 + colB] = hb;
          Y[((size_t)(t * 32) + 4 * g + j) * 512 + colB] = hb;
        }
      }
    }
    // ---- barrier B ----
    __syncthreads();
    if (tid == 0 && !dead) {
      gatom32(cntg, 1u);
      unsigned tgt = 32u * (unsigned)t + 32u;
      for (int it = 0;; ++it) {
        unsigned v = gatom32(cntg, 0u);
        if ((int)(v - tgt) >= 0) break;
        if (gatom32(abtg, 0u) != 0u) { dead = 1; break; }
        if (it >= (1 << 18)) { gatom32(abtg, 1u); dead = 1; break; }
        __builtin_amdgcn_s_sleep(2);
      }
    }
    __syncthreads();
    if (dead) break;
  }

  // protocol failure: poison output so validation fails fast & visibly
  if (dead && tid == 0) {
    for (int i = 0; i < 256; ++i)
      Y[(size_t)i * 32768 + (size_t)g * 256 + (size_t)role * 16] = 0x7F80;  // bf16 +inf
  }
}

// ---------------------------------------------------------------------------
// FC: logits[m][c] = Y1[m][:] @ fc_W[:][c] + fc_b[c]   (M=16384, N=128, K=512)
// ---------------------------------------------------------------------------
__global__ __launch_bounds__(256) void fc_kernel(const unsigned short* __restrict__ Y1,
                                                 const unsigned short* __restrict__ WtFC,
                                                 const float* __restrict__ fcb,
                                                 float* __restrict__ logits) {
  int w = threadIdx.x >> 6, l = threadIdx.x & 63;
  int cl = l & 15, kg = l >> 4;
  int m0 = blockIdx.x * 32, n0 = w * 32;
  v4f acc[2][2] = {};
#pragma unroll
  for (int kc = 0; kc < 16; ++kc) {
    int ko = kc * 32 + kg * 8;
    v8ss a0 = *(const v8ss*)&Y1[(size_t)(m0 + cl) * 512 + ko];
    v8ss a1 = *(const v8ss*)&Y1[(size_t)(m0 + 16 + cl) * 512 + ko];
    v8ss b0 = *(const v8ss*)&WtFC[(size_t)(n0 + cl) * 512 + ko];
    v8ss b1 = *(const v8ss*)&WtFC[(size_t)(n0 + 16 + cl) * 512 + ko];
    acc[0][0] = MFMA16(a0, b0, acc[0][0]);
    acc[0][1] = MFMA16(a0, b1, acc[0][1]);
    acc[1][0] = MFMA16(a1, b0, acc[1][0]);
    acc[1][1] = MFMA16(a1, b1, acc[1][1]);
  }
#pragma unroll
  for (int mi = 0; mi < 2; ++mi)
#pragma unroll
    for (int ni = 0; ni < 2; ++ni) {
      int col = n0 + ni * 16 + cl;
      float bias = fcb[col];
#pragma unroll
      for (int r = 0; r < 4; ++r) {
        int m = m0 + mi * 16 + kg * 4 + r;
        logits[(size_t)m * 128 + col] = acc[mi][ni][r] + bias;
      }
    }
}

// ---------------------------------------------------------------------------
// row-wise log_softmax over 128 cols; remap rows t-major -> out [B][S][128]
// ---------------------------------------------------------------------------
__global__ void lsm_kernel(const float* __restrict__ logits, float* __restrict__ out) {
  int w = threadIdx.x >> 6, l = threadIdx.x & 63;
  int row = blockIdx.x * 4 + w;  // 0..16383
  const float* x = &logits[(size_t)row * 128];
  float a = x[l], b2 = x[l + 64];
  float m = fmaxf(a, b2);
#pragma unroll
  for (int off = 32; off; off >>= 1) m = fmaxf(m, __shfl_xor(m, off));
  float s = __expf(a - m) + __expf(b2 - m);
#pragma unroll
  for (int off = 32; off; off >>= 1) s += __shfl_xor(s, off);
  float lse = m + logf(s);
  int t = row >> 5, bb = row & 31;
  float* o = &out[((size_t)bb * SS + t) * 128];
  o[l] = a - lse;
  o[l + 64] = b2 - lse;
}

// ---------------------------------------------------------------------------
extern "C" void kernel_launch(void* const* d_in, const int* in_sizes, int n_in,
                              void* d_out, int out_size, void* d_ws, size_t ws_size,
                              hipStream_t stream) {
  (void)in_sizes; (void)n_in; (void)out_size; (void)ws_size;
  const int*   tokens = (const int*)d_in[0];
  const float* emb    = (const float*)d_in[1];
  const float* l0Wz = (const float*)d_in[2];  const float* l0bz = (const float*)d_in[3];
  const float* l0Wr = (const float*)d_in[4];  const float* l0br = (const float*)d_in[5];
  const float* l0Wn = (const float*)d_in[6];  const float* l0bn = (const float*)d_in[7];
  const float* l1Wz = (const float*)d_in[8];  const float* l1bz = (const float*)d_in[9];
  const float* l1Wr = (const float*)d_in[10]; const float* l1br = (const float*)d_in[11];
  const float* l1Wn = (const float*)d_in[12]; const float* l1bn = (const float*)d_in[13];
  const float* fcW  = (const float*)d_in[14]; const float* fcb  = (const float*)d_in[15];

  char* ws = (char*)d_ws;
  unsigned* claim0 = (unsigned*)(ws + O_CLM0);
  unsigned* claim1 = (unsigned*)(ws + O_CLM1);
  unsigned* cnt0   = (unsigned*)(ws + O_CNT0);
  unsigned* cnt1   = (unsigned*)(ws + O_CNT1);
  unsigned* abt0   = (unsigned*)(ws + O_ABT0);
  unsigned* abt1   = (unsigned*)(ws + O_ABT1);
  unsigned short* hx0  = (unsigned short*)(ws + O_HX0);
  unsigned short* rhx0 = (unsigned short*)(ws + O_RHX0);
  unsigned short* hx1  = (unsigned short*)(ws + O_HX1);
  unsigned short* rhx1 = (unsigned short*)(ws + O_RHX1);
  unsigned short* Wt0x = (unsigned short*)(ws + O_WT0X);
  unsigned short* Wt0h = (unsigned short*)(ws + O_WT0H);
  unsigned short* Wt1x = (unsigned short*)(ws + O_WT1X);
  unsigned short* Wt1h = (unsigned short*)(ws + O_WT1H);
  unsigned short* WtFC = (unsigned short*)(ws + O_WTFC);
  unsigned short* Xemb = (unsigned short*)(ws + O_XEMB);
  unsigned short* Y0   = (unsigned short*)(ws + O_Y0);
  unsigned short* Y1   = (unsigned short*)(ws + O_Y1);
  float*          logits = (float*)(ws + O_LOGITS);
  unsigned short* Xp   = (unsigned short*)(ws + O_XP);

  // zero claim/cnt/abort + h/rh exchange buffers (runs every call/replay)
  hipMemsetAsync(ws, 0, O_ZERO_END, stream);

  prep_kernel<<<4096, 256, 0, stream>>>(l0Wz, l0Wr, l0Wn, l1Wz, l1Wr, l1Wn, fcW,
                                        Wt0x, Wt0h, Wt1x, Wt1h, WtFC);
  embed_kernel<<<MROWS, 256, 0, stream>>>(tokens, emb, Xemb);

  // layer 0: input projections (K=256), then XCD-local recurrence
  xproj_kernel<256><<<dim3(512, 12), 256, 0, stream>>>(Xemb, Wt0x, Xp);
  gru_rec2<<<256, 256, 0, stream>>>(Wt0h, Xp, Y0, hx0, rhx0, l0bz, l0br, l0bn,
                                    claim0, cnt0, abt0);
  // layer 1: input projections from Y0 (K=512), then recurrence
  xproj_kernel<512><<<dim3(512, 12), 256, 0, stream>>>(Y0, Wt1x, Xp);
  gru_rec2<<<256, 256, 0, stream>>>(Wt1h, Xp, Y1, hx1, rhx1, l1bz, l1br, l1bn,
                                    claim1, cnt1, abt1);

  fc_kernel<<<512, 256, 0, stream>>>(Y1, WtFC, fcb, logits);
  lsm_kernel<<<4096, 256, 0, stream>>>(logits, (float*)d_out);
}

// Round 7
// 5018.596 us; speedup vs baseline: 4.5037x; 1.3147x over previous
//
#include <hip/hip_runtime.h>
#include <hip/hip_bf16.h>
#include <cstdint>
#include <cstddef>

// ---------------------------------------------------------------------------
// MultilayerGRU: emb-gather -> GRU(256->512) -> GRU(512->512) -> FC(512->128)
//                -> log_softmax.   B=32, S=512, DI=256, DH=512, DO=128
//
// Round-7: DATAFLOW recurrence. No barriers, no flags: h / (r*h) exchange
// buffers have full time depth and are pre-memset to a sentinel (0x8080);
// consumers poll their 16B chunk until non-sentinel; producers publish via
// relaxed AGENT-scope atomic 8B stores (compiler-emitted -> guaranteed
// fabric visibility; non-RMW -> no r4 write storm) and never wait.
// Lesson bank: plain/sc0 stores are NOT cross-CU visible on gfx950
// (r2/r3/r5/r6); only fabric-level ops are (r1/r4).
// ---------------------------------------------------------------------------

typedef short v8ss __attribute__((ext_vector_type(8)));     // 8 bf16 (4 VGPR)
typedef float v4f  __attribute__((ext_vector_type(4)));
typedef unsigned short u16x4 __attribute__((ext_vector_type(4)));
typedef unsigned short u16x8 __attribute__((ext_vector_type(8)));
typedef unsigned long long u64;

#define MFMA16(a, b, c) __builtin_amdgcn_mfma_f32_16x16x32_bf16((a), (b), (c), 0, 0, 0)

__device__ __forceinline__ unsigned short f2bf(float f) {
  union { float f; unsigned u; } v; v.f = f;
  unsigned r = v.u + 0x7fffu + ((v.u >> 16) & 1u);   // RNE
  return (unsigned short)(r >> 16);
}
// published values must never equal the sentinel bf16 pattern 0x8080
__device__ __forceinline__ unsigned short f2bfp(float f) {
  unsigned short h = f2bf(f);
  return (h == 0x8080u) ? (unsigned short)0x8081u : h;   // |delta| ~ 1e-38
}
__device__ __forceinline__ float bf2f(unsigned short h) {
  union { unsigned u; float f; } v; v.u = ((unsigned)h) << 16; return v.f;
}

#define S64   0x8080808080808080ull
#define INF64 0x7F807F807F807F80ull
#define POLL_LIM 16384

__device__ __forceinline__ u64 aload(const u64* p) {
  return __hip_atomic_load(p, __ATOMIC_RELAXED, __HIP_MEMORY_SCOPE_AGENT);
}
__device__ __forceinline__ void astore(u64* p, u64 v) {
  __hip_atomic_store(p, v, __ATOMIC_RELAXED, __HIP_MEMORY_SCOPE_AGENT);
}
// poll one 8B chunk until non-sentinel (or WG-dead / timeout)
__device__ __forceinline__ u64 spin8(const u64* p, int* dead) {
  u64 v = aload(p);
  if (v != S64) return v;
  int it = 0;
  for (;;) {
    __builtin_amdgcn_s_sleep(2);
    v = aload(p);
    if (v != S64) return v;
    if (*(volatile int*)dead) return v;
    if (++it > POLL_LIM) { *(volatile int*)dead = 1; return v; }
  }
}

// ----- sizes -----
#define BB   32
#define SS   512
#define DI   256
#define DH   512
#define DO   128
#define MROWS (BB * SS)          // 16384, row index = t*32 + b
#define NGATE (3 * DH)           // 1536
#define WPG  16                  // worker WGs per group
#define SLAB 16384               // elems per time-slot: 32 batches x 512

// ----- ws offsets (bytes); total 106,364,928 <= proven-good 106.4MB -----
#define O_HX0   0                              // [513][32][512] bf16
#define O_HX1   16809984                       // [513][32][512] bf16
#define O_RHX   33619968                       // [512][32][512] bf16 (shared L0/L1)
#define O_XEMB  O_RHX                          // Xemb aliases rhx (dead before use)
#define O_WT0X  50397184                       // [1536][256] bf16
#define O_WT0H  (O_WT0X + 1536*256*2)          // [16][96][512] bf16
#define O_WT1X  (O_WT0H + 16*96*512*2)         // [1536][512] bf16
#define O_WT1H  (O_WT1X + 1536*512*2)          // [16][96][512] bf16
#define O_WTFC  (O_WT1H + 16*96*512*2)         // [128][512] bf16
#define O_XP    (O_WTFC + 128*512*2)           // [512][1536][32] bf16

// ---------------------------------------------------------------------------
// weight repack: f32 -> bf16 transposed layouts
// ---------------------------------------------------------------------------
__global__ void prep_kernel(const float* __restrict__ l0Wz, const float* __restrict__ l0Wr,
                            const float* __restrict__ l0Wn,
                            const float* __restrict__ l1Wz, const float* __restrict__ l1Wr,
                            const float* __restrict__ l1Wn,
                            const float* __restrict__ fcW,
                            unsigned short* __restrict__ Wt0x, unsigned short* __restrict__ Wt0h,
                            unsigned short* __restrict__ Wt1x, unsigned short* __restrict__ Wt1h,
                            unsigned short* __restrict__ WtFC) {
  const int n0 = 1536 * 256;        // Wt0x
  const int n1 = 16 * 96 * 512;     // Wt0h
  const int n2 = 1536 * 512;        // Wt1x
  const int n3 = 16 * 96 * 512;     // Wt1h
  const int n4 = 128 * 512;         // WtFC
  const int total = n0 + n1 + n2 + n3 + n4;
  for (int i = blockIdx.x * 256 + threadIdx.x; i < total; i += gridDim.x * 256) {
    int j = i;
    if (j < n0) {  // Wt0x[gcol][k] = l0_W{g}[k][c]
      int gcol = j / 256, k = j % 256, g = gcol >> 9, c = gcol & 511;
      const float* W = g == 0 ? l0Wz : (g == 1 ? l0Wr : l0Wn);
      Wt0x[j] = f2bf(W[k * 512 + c]); continue;
    }
    j -= n0;
    if (j < n1) {  // Wt0h[r][row][k] = l0_W{g(row)}[256+k][r*32 + (row&31)]
      int r = j / (96 * 512), rem = j % (96 * 512), row = rem / 512, k = rem % 512;
      int g = row >> 5, c = r * 32 + (row & 31);
      const float* W = g == 0 ? l0Wz : (g == 1 ? l0Wr : l0Wn);
      Wt0h[j] = f2bf(W[(256 + k) * 512 + c]); continue;
    }
    j -= n1;
    if (j < n2) {  // Wt1x[gcol][k] = l1_W{g}[k][c]
      int gcol = j / 512, k = j % 512, g = gcol >> 9, c = gcol & 511;
      const float* W = g == 0 ? l1Wz : (g == 1 ? l1Wr : l1Wn);
      Wt1x[j] = f2bf(W[k * 512 + c]); continue;
    }
    j -= n2;
    if (j < n3) {  // Wt1h[r][row][k] = l1_W{g(row)}[512+k][r*32 + (row&31)]
      int r = j / (96 * 512), rem = j % (96 * 512), row = rem / 512, k = rem % 512;
      int g = row >> 5, c = r * 32 + (row & 31);
      const float* W = g == 0 ? l1Wz : (g == 1 ? l1Wr : l1Wn);
      Wt1h[j] = f2bf(W[(512 + k) * 512 + c]); continue;
    }
    j -= n3;
    { int c = j / 512, k = j % 512; WtFC[j] = f2bf(fcW[k * 128 + c]); }
  }
}

// ---------------------------------------------------------------------------
// embedding gather
// ---------------------------------------------------------------------------
__global__ void embed_kernel(const int* __restrict__ tokens, const float* __restrict__ emb,
                             unsigned short* __restrict__ Xemb) {
  int r = blockIdx.x;            // 0..16383  (t-major)
  int c = threadIdx.x;           // 0..255
  int t = r >> 5, b = r & 31;
  int tok = tokens[b * SS + t];
  Xemb[(size_t)r * DI + c] = f2bf(emb[(size_t)tok * DI + c]);
}

// ---------------------------------------------------------------------------
// batched input projection: Xp[t][gcol][b]  (A:[16384][K], Bt:[1536][K])
// ---------------------------------------------------------------------------
template <int K>
__global__ __launch_bounds__(256) void xproj_kernel(const unsigned short* __restrict__ A,
                                                    const unsigned short* __restrict__ Bt,
                                                    unsigned short* __restrict__ Xp) {
  int w = threadIdx.x >> 6, l = threadIdx.x & 63;
  int cl = l & 15, kg = l >> 4;
  int m0 = blockIdx.x * 32;
  int n0 = blockIdx.y * 128 + w * 32;
  v4f acc[2][2] = {};
#pragma unroll
  for (int kc = 0; kc < K / 32; ++kc) {
    int ko = kc * 32 + kg * 8;
    v8ss a0 = *(const v8ss*)&A[(size_t)(m0 + cl) * K + ko];
    v8ss a1 = *(const v8ss*)&A[(size_t)(m0 + 16 + cl) * K + ko];
    v8ss b0 = *(const v8ss*)&Bt[(size_t)(n0 + cl) * K + ko];
    v8ss b1 = *(const v8ss*)&Bt[(size_t)(n0 + 16 + cl) * K + ko];
    acc[0][0] = MFMA16(a0, b0, acc[0][0]);
    acc[0][1] = MFMA16(a0, b1, acc[0][1]);
    acc[1][0] = MFMA16(a1, b0, acc[1][0]);
    acc[1][1] = MFMA16(a1, b1, acc[1][1]);
  }
  int t = blockIdx.x;
#pragma unroll
  for (int mi = 0; mi < 2; ++mi)
#pragma unroll
    for (int ni = 0; ni < 2; ++ni) {
      int col = n0 + ni * 16 + cl;
      int bb0 = mi * 16 + kg * 4;
      u16x4 o;
      o[0] = f2bf(acc[mi][ni][0]); o[1] = f2bf(acc[mi][ni][1]);
      o[2] = f2bf(acc[mi][ni][2]); o[3] = f2bf(acc[mi][ni][3]);
      *(u16x4*)&Xp[((size_t)t * NGATE + col) * 32 + bb0] = o;
    }
}

// ---------------------------------------------------------------------------
// dataflow GRU recurrence (round 7). 128 WGs: group g=blk>>4 (batches 4g..4g+3),
// role r=blk&15 (h-cols 32r..32r+31). hx:[513][32][512], rhx:[512][32][512],
// sentinel-initialized; publish = relaxed agent atomic 8B stores.
// ---------------------------------------------------------------------------
__global__ __launch_bounds__(256) void gru_rec3(
    const unsigned short* __restrict__ WtH,  // [16][96][512]
    const unsigned short* __restrict__ Xp,   // [512][1536][32]
    unsigned short* hx,                       // [513][32][512]
    unsigned short* rhx,                      // [512][32][512]
    const float* __restrict__ bz, const float* __restrict__ br,
    const float* __restrict__ bn) {
  __shared__ unsigned short Wt[96 * 520];
  __shared__ unsigned short At[16 * 520];
  __shared__ unsigned short Rt[16 * 520];
  __shared__ float zbuf[4 * 32];
  __shared__ float hbuf[4 * 32];
  __shared__ unsigned short rstage[4 * 32];
  __shared__ unsigned short hstage[4 * 32];
  __shared__ int dead;

  const int tid = threadIdx.x;
  const int g = blockIdx.x >> 4, role = blockIdx.x & 15;
  if (tid == 0) dead = 0;

  // recurrent-weight slice -> LDS (96 rows x 512)
  for (int ch = tid; ch < 96 * 64; ch += 256) {
    int row = ch >> 6, off = (ch & 63) * 8;
    *(u16x8*)&Wt[row * 520 + off] = *(const u16x8*)&WtH[((size_t)role * 96 + row) * 512 + off];
  }
  // zero At/Rt (rows 4-15 stay zero = MFMA row padding) and z/h state
  for (int i = tid * 8; i < 16 * 520; i += 256 * 8) {
    *(u16x8*)&At[i] = (u16x8)0;
    *(u16x8*)&Rt[i] = (u16x8)0;
  }
  if (tid < 128) { zbuf[tid] = 0.f; hbuf[tid] = 0.f; }
  __syncthreads();

  const int w = tid >> 6, l = tid & 63, cl = l & 15, kg = l >> 4;
  const int gate = w >> 1;             // phase A: waves 0,1 = Z; waves 2,3 = R
  const int lc16 = (w & 1) * 16;
  const int colA = role * 32 + lc16 + cl;
  const float biasA = (gate ? br : bz)[colA];
  const int lc16b = w * 16;            // phase B: waves 0,1 only
  const int colB = role * 32 + (lc16b & 31) + cl;
  const float biasB = (w < 2) ? bn[colB] : 0.f;

  // per-thread chunk offsets (elems): slot*SLAB + g*2048 + tid*8
  const size_t gofs = (size_t)g * 2048;
  u64* atdst = (u64*)&At[(tid >> 6) * 520 + (tid & 63) * 8];
  u64* rtdst = (u64*)&Rt[(tid >> 6) * 520 + (tid & 63) * 8];
  // publisher mapping (tid<32): j=tid>>3, 8B chunk c8=tid&7
  const size_t pubofs = gofs + (size_t)(tid >> 3) * 512 + role * 32 + (tid & 7) * 4;

  int t = 0;
  for (; t < SS; ++t) {
    // ---- stage h(t) -> At : poll own 16B chunk ----
    {
      const u64* p = (const u64*)(hx + (size_t)t * SLAB + gofs) + tid * 2;
      u64 lo = spin8(p, &dead), hi = spin8(p + 1, &dead);
      atdst[0] = lo; atdst[1] = hi;
    }
    __syncthreads();
    if (dead) break;

    // ---- phase A: Z | R (16 cols per wave), MFMA over At ----
    {
      u16x4 xp4 = *(const u16x4*)&Xp[((size_t)t * NGATE + gate * 512 + colA) * 32 + 4 * g];
      v4f acc = {};
#pragma unroll
      for (int kc = 0; kc < 16; ++kc) {
        int ko = kc * 32 + kg * 8;
        v8ss a = *(const v8ss*)&At[cl * 520 + ko];
        v8ss b = *(const v8ss*)&Wt[(gate * 32 + lc16 + cl) * 520 + ko];
        acc = MFMA16(a, b, acc);
      }
      if (l < 16) {   // lanes 0-15 hold rows 0-3 (the 4 real batches)
        int lc = lc16 + cl;
#pragma unroll
        for (int j = 0; j < 4; ++j) {
          float pre = acc[j] + bf2f(xp4[j]) + biasA;
          float gv = 1.f / (1.f + __expf(-pre));
          if (gate == 0) zbuf[j * 32 + lc] = gv;
          else           rstage[j * 32 + lc] = f2bfp(gv * hbuf[j * 32 + lc]);
        }
      }
    }
    __syncthreads();

    // ---- publish rh(t) (fire-and-forget) ----
    if (tid < 32)
      astore((u64*)(rhx + (size_t)t * SLAB + pubofs),
             *(const u64*)&rstage[(tid >> 3) * 32 + (tid & 7) * 4]);

    // ---- stage rh(t) -> Rt : poll ----
    {
      const u64* p = (const u64*)(rhx + (size_t)t * SLAB + gofs) + tid * 2;
      u64 lo = spin8(p, &dead), hi = spin8(p + 1, &dead);
      rtdst[0] = lo; rtdst[1] = hi;
    }
    __syncthreads();
    if (dead) break;

    // ---- phase B: N gate + state update (waves 0,1) ----
    if (w < 2) {
      u16x4 xpn = *(const u16x4*)&Xp[((size_t)t * NGATE + 1024 + colB) * 32 + 4 * g];
      v4f acc = {};
#pragma unroll
      for (int kc = 0; kc < 16; ++kc) {
        int ko = kc * 32 + kg * 8;
        v8ss a = *(const v8ss*)&Rt[cl * 520 + ko];
        v8ss b = *(const v8ss*)&Wt[(64 + lc16b + cl) * 520 + ko];
        acc = MFMA16(a, b, acc);
      }
      if (l < 16) {
        int lc = lc16b + cl;
#pragma unroll
        for (int j = 0; j < 4; ++j) {
          float pre = acc[j] + bf2f(xpn[j]) + biasB;
          float ht = 1.f - 2.f / (__expf(2.f * pre) + 1.f);   // overflow-safe tanh
          float z = zbuf[j * 32 + lc];
          float hn = (1.f - z) * hbuf[j * 32 + lc] + z * ht;
          hbuf[j * 32 + lc] = hn;
          hstage[j * 32 + lc] = f2bfp(hn);
        }
      }
    }
    __syncthreads();

    // ---- publish h(t+1) (fire-and-forget) ----
    if (tid < 32)
      astore((u64*)(hx + (size_t)(t + 1) * SLAB + pubofs),
             *(const u64*)&hstage[(tid >> 3) * 32 + (tid & 7) * 4]);
  }

  // timeout: poison own chunks (non-sentinel inf) so consumers unblock fast
  // and validation fails visibly
  if (dead) {
    for (int s = tid; s < SS * 8; s += 256) {
      int t2 = s >> 3, c8 = s & 7;
      size_t o = gofs + role * 32 + c8 * 4;
#pragma unroll
      for (int j = 0; j < 4; ++j) {
        astore((u64*)(hx + (size_t)(t2 + 1) * SLAB + o + (size_t)j * 512), INF64);
        astore((u64*)(rhx + (size_t)t2 * SLAB + o + (size_t)j * 512), INF64);
      }
    }
  }
}

// ---------------------------------------------------------------------------
// fused FC + log_softmax: per block, rows m0..m0+31, all 128 cols.
// ---------------------------------------------------------------------------
__global__ __launch_bounds__(256) void fc_lsm_kernel(const unsigned short* __restrict__ Y1,
                                                     const unsigned short* __restrict__ WtFC,
                                                     const float* __restrict__ fcb,
                                                     float* __restrict__ out) {
  __shared__ float lout[32 * 128];
  int w = threadIdx.x >> 6, l = threadIdx.x & 63;
  int cl = l & 15, kg = l >> 4;
  int m0 = blockIdx.x * 32, n0 = w * 32;
  v4f acc[2][2] = {};
#pragma unroll
  for (int kc = 0; kc < 16; ++kc) {
    int ko = kc * 32 + kg * 8;
    v8ss a0 = *(const v8ss*)&Y1[(size_t)(m0 + cl) * 512 + ko];
    v8ss a1 = *(const v8ss*)&Y1[(size_t)(m0 + 16 + cl) * 512 + ko];
    v8ss b0 = *(const v8ss*)&WtFC[(size_t)(n0 + cl) * 512 + ko];
    v8ss b1 = *(const v8ss*)&WtFC[(size_t)(n0 + 16 + cl) * 512 + ko];
    acc[0][0] = MFMA16(a0, b0, acc[0][0]);
    acc[0][1] = MFMA16(a0, b1, acc[0][1]);
    acc[1][0] = MFMA16(a1, b0, acc[1][0]);
    acc[1][1] = MFMA16(a1, b1, acc[1][1]);
  }
#pragma unroll
  for (int mi = 0; mi < 2; ++mi)
#pragma unroll
    for (int ni = 0; ni < 2; ++ni) {
      int col = n0 + ni * 16 + cl;
      float bias = fcb[col];
#pragma unroll
      for (int r = 0; r < 4; ++r)
        lout[(mi * 16 + kg * 4 + r) * 128 + col] = acc[mi][ni][r] + bias;
    }
  __syncthreads();

  // wave w reduces rows w*8 .. w*8+7
  for (int rr = 0; rr < 8; ++rr) {
    int lr = w * 8 + rr;
    float a = lout[lr * 128 + l], b2 = lout[lr * 128 + 64 + l];
    float m = fmaxf(a, b2);
#pragma unroll
    for (int off = 32; off; off >>= 1) m = fmaxf(m, __shfl_xor(m, off));
    float s = __expf(a - m) + __expf(b2 - m);
#pragma unroll
    for (int off = 32; off; off >>= 1) s += __shfl_xor(s, off);
    float lse = m + logf(s);
    int mrow = m0 + lr, t = mrow >> 5, bb = mrow & 31;
    float* o = &out[((size_t)bb * SS + t) * 128];
    o[l] = a - lse;
    o[l + 64] = b2 - lse;
  }
}

// ---------------------------------------------------------------------------
extern "C" void kernel_launch(void* const* d_in, const int* in_sizes, int n_in,
                              void* d_out, int out_size, void* d_ws, size_t ws_size,
                              hipStream_t stream) {
  (void)in_sizes; (void)n_in; (void)out_size; (void)ws_size;
  const int*   tokens = (const int*)d_in[0];
  const float* emb    = (const float*)d_in[1];
  const float* l0Wz = (const float*)d_in[2];  const float* l0bz = (const float*)d_in[3];
  const float* l0Wr = (const float*)d_in[4];  const float* l0br = (const float*)d_in[5];
  const float* l0Wn = (const float*)d_in[6];  const float* l0bn = (const float*)d_in[7];
  const float* l1Wz = (const float*)d_in[8];  const float* l1bz = (const float*)d_in[9];
  const float* l1Wr = (const float*)d_in[10]; const float* l1br = (const float*)d_in[11];
  const float* l1Wn = (const float*)d_in[12]; const float* l1bn = (const float*)d_in[13];
  const float* fcW  = (const float*)d_in[14]; const float* fcb  = (const float*)d_in[15];

  char* ws = (char*)d_ws;
  unsigned short* hx0  = (unsigned short*)(ws + O_HX0);
  unsigned short* hx1  = (unsigned short*)(ws + O_HX1);
  unsigned short* rhx  = (unsigned short*)(ws + O_RHX);
  unsigned short* Xemb = (unsigned short*)(ws + O_XEMB);   // aliases rhx region
  unsigned short* Wt0x = (unsigned short*)(ws + O_WT0X);
  unsigned short* Wt0h = (unsigned short*)(ws + O_WT0H);
  unsigned short* Wt1x = (unsigned short*)(ws + O_WT1X);
  unsigned short* Wt1h = (unsigned short*)(ws + O_WT1H);
  unsigned short* WtFC = (unsigned short*)(ws + O_WTFC);
  unsigned short* Xp   = (unsigned short*)(ws + O_XP);

  // h slabs: slot 0 = zeros (h0), slots 1..512 = sentinel
  hipMemsetAsync(hx0, 0x00, 32768, stream);
  hipMemsetAsync((char*)hx0 + 32768, 0x80, (size_t)SS * 32768, stream);
  hipMemsetAsync(hx1, 0x00, 32768, stream);
  hipMemsetAsync((char*)hx1 + 32768, 0x80, (size_t)SS * 32768, stream);

  prep_kernel<<<4096, 256, 0, stream>>>(l0Wz, l0Wr, l0Wn, l1Wz, l1Wr, l1Wn, fcW,
                                        Wt0x, Wt0h, Wt1x, Wt1h, WtFC);
  embed_kernel<<<MROWS, 256, 0, stream>>>(tokens, emb, Xemb);
  xproj_kernel<256><<<dim3(512, 12), 256, 0, stream>>>(Xemb, Wt0x, Xp);

  // Xemb now dead -> sentinel the rhx region, run layer-0 recurrence
  hipMemsetAsync(rhx, 0x80, (size_t)SS * 32768, stream);
  gru_rec3<<<128, 256, 0, stream>>>(Wt0h, Xp, hx0, rhx, l0bz, l0br, l0bn);

  // layer-1 input projections read y0 = hx0 slots 1..512
  xproj_kernel<512><<<dim3(512, 12), 256, 0, stream>>>(hx0 + SLAB, Wt1x, Xp);

  hipMemsetAsync(rhx, 0x80, (size_t)SS * 32768, stream);
  gru_rec3<<<128, 256, 0, stream>>>(Wt1h, Xp, hx1, rhx, l1bz, l1br, l1bn);

  fc_lsm_kernel<<<512, 256, 0, stream>>>(hx1 + SLAB, WtFC, fcb, (float*)d_out);
}

// Round 8
// 3249.821 us; speedup vs baseline: 6.9550x; 1.5443x over previous
//
#include <hip/hip_runtime.h>
#include <hip/hip_bf16.h>
#include <cstdint>
#include <cstddef>

// ---------------------------------------------------------------------------
// MultilayerGRU: emb-gather -> GRU(256->512) -> GRU(512->512) -> FC(512->128)
//                -> log_softmax.   B=32, S=512, DI=256, DH=512, DO=128
//
// Round-8: LAYER-PIPELINED dataflow. One 256-WG kernel runs both layers
// concurrently (blocks 0-127 = L0, 128-255 = L1). L1 consumes L0's h-slabs
// (hx0[t+1] = y0(t)) via the r7 sentinel-poll protocol. Input projections are
// fused into the step loop: acc  =  x_t @ Wx (B streamed from L2)  +  h @ Wh
// (LDS-resident), all f32 in the MFMA accumulator. No Xp buffer, no xproj
// kernels, no barriers. Cross-WG data: relaxed AGENT atomic 8B store/load
// (the only primitives proven cross-CU-visible on gfx950: r1-r7 evidence).
// ---------------------------------------------------------------------------

typedef short v8ss __attribute__((ext_vector_type(8)));     // 8 bf16 (4 VGPR)
typedef float v4f  __attribute__((ext_vector_type(4)));
typedef unsigned short u16x8 __attribute__((ext_vector_type(8)));
typedef unsigned long long u64;

#define MFMA16(a, b, c) __builtin_amdgcn_mfma_f32_16x16x32_bf16((a), (b), (c), 0, 0, 0)

__device__ __forceinline__ unsigned short f2bf(float f) {
  union { float f; unsigned u; } v; v.f = f;
  unsigned r = v.u + 0x7fffu + ((v.u >> 16) & 1u);   // RNE
  return (unsigned short)(r >> 16);
}
// published values must never equal the sentinel bf16 pattern 0x8080
__device__ __forceinline__ unsigned short f2bfp(float f) {
  unsigned short h = f2bf(f);
  return (h == 0x8080u) ? (unsigned short)0x8081u : h;   // |delta| ~ 1e-38
}
__device__ __forceinline__ float bf2f(unsigned short h) {
  union { unsigned u; float f; } v; v.u = ((unsigned)h) << 16; return v.f;
}

#define S64   0x8080808080808080ull
#define INF64 0x7F807F807F807F80ull
#define POLL_LIM 16384

__device__ __forceinline__ u64 aload(const u64* p) {
  return __hip_atomic_load(p, __ATOMIC_RELAXED, __HIP_MEMORY_SCOPE_AGENT);
}
__device__ __forceinline__ void astore(u64* p, u64 v) {
  __hip_atomic_store(p, v, __ATOMIC_RELAXED, __HIP_MEMORY_SCOPE_AGENT);
}
// poll one 8B chunk until non-sentinel (or WG-dead / timeout)
__device__ __forceinline__ u64 spin8(const u64* p, int* dead) {
  u64 v = aload(p);
  if (v != S64) return v;
  int it = 0;
  for (;;) {
    __builtin_amdgcn_s_sleep(1);
    v = aload(p);
    if (v != S64) return v;
    if (*(volatile int*)dead) return v;
    if (++it > POLL_LIM) { *(volatile int*)dead = 1; return v; }
  }
}

// ----- sizes -----
#define BB   32
#define SS   512
#define DI   256
#define DH   512
#define DO   128
#define MROWS (BB * SS)          // 16384, row index = t*32 + b
#define SLAB 16384               // elems per time-slot: 32 batches x 512

// ----- ws offsets (bytes); total ~81.2 MB (<= proven 106.4 MB) -----
#define O_HX0   0                              // [513][32][512] bf16
#define O_HX1   16809984                       // [513][32][512] bf16
#define O_RHX0  33619968                       // [512][32][512] bf16
#define O_RHX1  50397184                       // [512][32][512] bf16
#define O_WT0X  67174400                       // [1536][256] bf16 (streamed)
#define O_WT0H  (O_WT0X + 1536*256*2)          // [16][96][512] bf16
#define O_WT1X  (O_WT0H + 16*96*512*2)         // [1536][512] bf16 (streamed)
#define O_WT1H  (O_WT1X + 1536*512*2)          // [16][96][512] bf16
#define O_WTFC  (O_WT1H + 16*96*512*2)         // [128][512] bf16
#define O_XEMB  (O_WTFC + 128*512*2)           // [16384][256] bf16

// ---------------------------------------------------------------------------
// weight repack: f32 -> bf16 transposed layouts
// ---------------------------------------------------------------------------
__global__ void prep_kernel(const float* __restrict__ l0Wz, const float* __restrict__ l0Wr,
                            const float* __restrict__ l0Wn,
                            const float* __restrict__ l1Wz, const float* __restrict__ l1Wr,
                            const float* __restrict__ l1Wn,
                            const float* __restrict__ fcW,
                            unsigned short* __restrict__ Wt0x, unsigned short* __restrict__ Wt0h,
                            unsigned short* __restrict__ Wt1x, unsigned short* __restrict__ Wt1h,
                            unsigned short* __restrict__ WtFC) {
  const int n0 = 1536 * 256;        // Wt0x
  const int n1 = 16 * 96 * 512;     // Wt0h
  const int n2 = 1536 * 512;        // Wt1x
  const int n3 = 16 * 96 * 512;     // Wt1h
  const int n4 = 128 * 512;         // WtFC
  const int total = n0 + n1 + n2 + n3 + n4;
  for (int i = blockIdx.x * 256 + threadIdx.x; i < total; i += gridDim.x * 256) {
    int j = i;
    if (j < n0) {  // Wt0x[gcol][k] = l0_W{g}[k][c]
      int gcol = j / 256, k = j % 256, g = gcol >> 9, c = gcol & 511;
      const float* W = g == 0 ? l0Wz : (g == 1 ? l0Wr : l0Wn);
      Wt0x[j] = f2bf(W[k * 512 + c]); continue;
    }
    j -= n0;
    if (j < n1) {  // Wt0h[r][row][k] = l0_W{g(row)}[256+k][r*32 + (row&31)]
      int r = j / (96 * 512), rem = j % (96 * 512), row = rem / 512, k = rem % 512;
      int g = row >> 5, c = r * 32 + (row & 31);
      const float* W = g == 0 ? l0Wz : (g == 1 ? l0Wr : l0Wn);
      Wt0h[j] = f2bf(W[(256 + k) * 512 + c]); continue;
    }
    j -= n1;
    if (j < n2) {  // Wt1x[gcol][k] = l1_W{g}[k][c]
      int gcol = j / 512, k = j % 512, g = gcol >> 9, c = gcol & 511;
      const float* W = g == 0 ? l1Wz : (g == 1 ? l1Wr : l1Wn);
      Wt1x[j] = f2bf(W[k * 512 + c]); continue;
    }
    j -= n2;
    if (j < n3) {  // Wt1h[r][row][k] = l1_W{g(row)}[512+k][r*32 + (row&31)]
      int r = j / (96 * 512), rem = j % (96 * 512), row = rem / 512, k = rem % 512;
      int g = row >> 5, c = r * 32 + (row & 31);
      const float* W = g == 0 ? l1Wz : (g == 1 ? l1Wr : l1Wn);
      Wt1h[j] = f2bf(W[(512 + k) * 512 + c]); continue;
    }
    j -= n3;
    { int c = j / 512, k = j % 512; WtFC[j] = f2bf(fcW[k * 128 + c]); }
  }
}

// ---------------------------------------------------------------------------
// embedding gather
// ---------------------------------------------------------------------------
__global__ void embed_kernel(const int* __restrict__ tokens, const float* __restrict__ emb,
                             unsigned short* __restrict__ Xemb) {
  int r = blockIdx.x;            // 0..16383  (t-major)
  int c = threadIdx.x;           // 0..255
  int t = r >> 5, b = r & 31;
  int tok = tokens[b * SS + t];
  Xemb[(size_t)r * DI + c] = f2bf(emb[(size_t)tok * DI + c]);
}

// ---------------------------------------------------------------------------
// fused pipelined GRU body (one layer instance per WG).
// group g owns batches 4g..4g+3; role owns h-cols 32r..32r+31.
// acc = x_t@Wx (streamed from L2) + h@Wh (LDS) in f32, then gates.
// ---------------------------------------------------------------------------
template <int LAYER>
__device__ __forceinline__ void gru_body(
    const int g, const int role, const int tid,
    const unsigned short* __restrict__ WtH,   // [16][96][512]
    const unsigned short* __restrict__ Wx,    // [1536][K]
    const unsigned short* __restrict__ Xe,    // Xemb (L0 only)
    unsigned short* hx0,                      // x-source slabs (L1 only)
    unsigned short* hx, unsigned short* rhx,
    const float* __restrict__ bz, const float* __restrict__ br,
    const float* __restrict__ bn,
    unsigned short* Wt, unsigned short* At, unsigned short* Rt, unsigned short* Xt,
    float* zbuf, float* hbuf, unsigned short* rstage, unsigned short* hstage,
    int* dead) {
  constexpr int K = LAYER ? 512 : 256;

  // recurrent-weight slice -> LDS (96 rows x 512)
  for (int ch = tid; ch < 96 * 64; ch += 256) {
    int row = ch >> 6, off = (ch & 63) * 8;
    *(u16x8*)&Wt[row * 520 + off] = *(const u16x8*)&WtH[((size_t)role * 96 + row) * 512 + off];
  }
  // zero staging tiles (rows 4-15 stay zero = MFMA row padding) and state
  for (int i = tid * 8; i < 16 * 520; i += 256 * 8) {
    *(u16x8*)&At[i] = (u16x8)0;
    *(u16x8*)&Rt[i] = (u16x8)0;
    *(u16x8*)&Xt[i] = (u16x8)0;
  }
  if (tid < 128) { zbuf[tid] = 0.f; hbuf[tid] = 0.f; }
  __syncthreads();

  const int w = tid >> 6, l = tid & 63, cl = l & 15, kg = l >> 4;
  const int gate = w >> 1;             // phase A: waves 0,1 = Z; waves 2,3 = R
  const int lc16 = (w & 1) * 16;
  const int colA = role * 32 + lc16 + cl;
  const float biasA = (gate ? br : bz)[colA];
  const int lc16b = (w & 1) * 16;      // phase B (waves 0,1 only)
  const int colB = role * 32 + lc16b + cl;
  const float biasB = (w < 2) ? bn[colB] : 0.f;

  const size_t gofs = (size_t)g * 2048;
  u64* atdst = (u64*)&At[(tid >> 6) * 520 + (tid & 63) * 8];
  u64* xtdst = (u64*)&Xt[(tid >> 6) * 520 + (tid & 63) * 8];
  const size_t pubofs = gofs + (size_t)(tid >> 3) * 512 + role * 32 + (tid & 7) * 4;
  const unsigned short* WxA = Wx + (size_t)(gate * 512 + colA) * K;   // lane's phase-A row
  const unsigned short* WxB = Wx + (size_t)(1024 + colB) * K;         // lane's phase-B row

  for (int t = 0; t < SS; ++t) {
    // ---- stage x_t ----
    if (LAYER == 0) {
      if (tid < 128) {  // static embeddings: plain loads, 4 rows x 256 bf16
        int j = tid >> 5, off = (tid & 31) * 8;
        *(u16x8*)&Xt[j * 520 + off] =
            *(const u16x8*)&Xe[((size_t)(t * 32) + 4 * g + j) * 256 + off];
      }
    } else {            // y0(t) = hx0[t+1]: sentinel-poll
      const u64* p = (const u64*)(hx0 + (size_t)(t + 1) * SLAB + gofs) + tid * 2;
      u64 lo = spin8(p, dead), hi = spin8(p + 1, dead);
      xtdst[0] = lo; xtdst[1] = hi;
    }
    // ---- stage own h(t) ----
    {
      const u64* p = (const u64*)(hx + (size_t)t * SLAB + gofs) + tid * 2;
      u64 lo = spin8(p, dead), hi = spin8(p + 1, dead);
      atdst[0] = lo; atdst[1] = hi;
    }
    __syncthreads();
    if (*(volatile int*)dead) break;

    // ---- phase A: acc = x@WxA + h@WhA ; Z gate | R gate ----
    {
      v4f acc = {};
#pragma unroll
      for (int kc = 0; kc < K / 32; ++kc) {
        int ko = kc * 32 + kg * 8;
        v8ss a = *(const v8ss*)&Xt[cl * 520 + ko];
        v8ss b = *(const v8ss*)&WxA[ko];
        acc = MFMA16(a, b, acc);
      }
#pragma unroll
      for (int kc = 0; kc < 16; ++kc) {
        int ko = kc * 32 + kg * 8;
        v8ss a = *(const v8ss*)&At[cl * 520 + ko];
        v8ss b = *(const v8ss*)&Wt[(gate * 32 + lc16 + cl) * 520 + ko];
        acc = MFMA16(a, b, acc);
      }
      if (l < 16) {   // lanes 0-15 hold rows 0-3 (the 4 real batches)
        int lc = lc16 + cl;
#pragma unroll
        for (int j = 0; j < 4; ++j) {
          float pre = acc[j] + biasA;
          float gv = 1.f / (1.f + __expf(-pre));
          if (gate == 0) zbuf[j * 32 + lc] = gv;
          else           rstage[j * 32 + lc] = f2bfp(gv * hbuf[j * 32 + lc]);
        }
      }
    }
    __syncthreads();
    // ---- publish rh(t) ----
    if (tid < 32)
      astore((u64*)(rhx + (size_t)t * SLAB + pubofs),
             *(const u64*)&rstage[(tid >> 3) * 32 + (tid & 7) * 4]);

    // ---- waves 2,3: stage rh -> Rt (poll) ; waves 0,1: phase-B xp overlap ----
    v4f accB = {};
    if (w >= 2) {
      int tt = tid & 127;
      int row = tt >> 5, c16 = (tt & 31) * 16;
      const u64* p = (const u64*)(rhx + (size_t)t * SLAB + gofs + (size_t)row * 512 + c16);
      u64* d = (u64*)&Rt[row * 520 + c16];
      d[0] = spin8(p, dead);     d[1] = spin8(p + 1, dead);
      d[2] = spin8(p + 2, dead); d[3] = spin8(p + 3, dead);
    } else {
#pragma unroll
      for (int kc = 0; kc < K / 32; ++kc) {
        int ko = kc * 32 + kg * 8;
        v8ss a = *(const v8ss*)&Xt[cl * 520 + ko];
        v8ss b = *(const v8ss*)&WxB[ko];
        accB = MFMA16(a, b, accB);
      }
    }
    __syncthreads();
    if (*(volatile int*)dead) break;

    // ---- phase B: N gate + state update (waves 0,1) ----
    if (w < 2) {
#pragma unroll
      for (int kc = 0; kc < 16; ++kc) {
        int ko = kc * 32 + kg * 8;
        v8ss a = *(const v8ss*)&Rt[cl * 520 + ko];
        v8ss b = *(const v8ss*)&Wt[(64 + lc16b + cl) * 520 + ko];
        accB = MFMA16(a, b, accB);
      }
      if (l < 16) {
        int lc = lc16b + cl;
#pragma unroll
        for (int j = 0; j < 4; ++j) {
          float pre = accB[j] + biasB;
          float ht = 1.f - 2.f / (__expf(2.f * pre) + 1.f);   // overflow-safe tanh
          float z = zbuf[j * 32 + lc];
          float hn = (1.f - z) * hbuf[j * 32 + lc] + z * ht;
          hbuf[j * 32 + lc] = hn;
          hstage[j * 32 + lc] = f2bfp(hn);
        }
      }
    }
    __syncthreads();
    // ---- publish h(t+1) ----
    if (tid < 32)
      astore((u64*)(hx + (size_t)(t + 1) * SLAB + pubofs),
             *(const u64*)&hstage[(tid >> 3) * 32 + (tid & 7) * 4]);
  }

  // timeout: poison own chunks so consumers unblock & validation fails fast
  if (*(volatile int*)dead) {
    for (int s = tid; s < SS * 8; s += 256) {
      int t2 = s >> 3, c8 = s & 7;
      size_t o = gofs + role * 32 + c8 * 4;
#pragma unroll
      for (int j = 0; j < 4; ++j) {
        astore((u64*)(hx + (size_t)(t2 + 1) * SLAB + o + (size_t)j * 512), INF64);
        astore((u64*)(rhx + (size_t)t2 * SLAB + o + (size_t)j * 512), INF64);
      }
    }
  }
}

__global__ __launch_bounds__(256, 1) void gru_fused(
    const unsigned short* __restrict__ Wt0h, const unsigned short* __restrict__ Wt1h,
    const unsigned short* __restrict__ Wt0x, const unsigned short* __restrict__ Wt1x,
    const unsigned short* __restrict__ Xemb,
    unsigned short* hx0, unsigned short* rhx0,
    unsigned short* hx1, unsigned short* rhx1,
    const float* bz0, const float* br0, const float* bn0,
    const float* bz1, const float* br1, const float* bn1) {
  __shared__ unsigned short Wt[96 * 520];
  __shared__ unsigned short At[16 * 520];
  __shared__ unsigned short Rt[16 * 520];
  __shared__ unsigned short Xt[16 * 520];
  __shared__ float zbuf[128], hbuf[128];
  __shared__ unsigned short rstage[128], hstage[128];
  __shared__ int dead;
  const int tid = threadIdx.x;
  if (tid == 0) dead = 0;
  const int layer = blockIdx.x >> 7, id = blockIdx.x & 127;
  const int g = id >> 4, role = id & 15;
  if (layer == 0)
    gru_body<0>(g, role, tid, Wt0h, Wt0x, Xemb, nullptr, hx0, rhx0, bz0, br0, bn0,
                Wt, At, Rt, Xt, zbuf, hbuf, rstage, hstage, &dead);
  else
    gru_body<1>(g, role, tid, Wt1h, Wt1x, nullptr, hx0, hx1, rhx1, bz1, br1, bn1,
                Wt, At, Rt, Xt, zbuf, hbuf, rstage, hstage, &dead);
}

// ---------------------------------------------------------------------------
// fused FC + log_softmax: per block, rows m0..m0+31, all 128 cols.
// ---------------------------------------------------------------------------
__global__ __launch_bounds__(256) void fc_lsm_kernel(const unsigned short* __restrict__ Y1,
                                                     const unsigned short* __restrict__ WtFC,
                                                     const float* __restrict__ fcb,
                                                     float* __restrict__ out) {
  __shared__ float lout[32 * 128];
  int w = threadIdx.x >> 6, l = threadIdx.x & 63;
  int cl = l & 15, kg = l >> 4;
  int m0 = blockIdx.x * 32, n0 = w * 32;
  v4f acc[2][2] = {};
#pragma unroll
  for (int kc = 0; kc < 16; ++kc) {
    int ko = kc * 32 + kg * 8;
    v8ss a0 = *(const v8ss*)&Y1[(size_t)(m0 + cl) * 512 + ko];
    v8ss a1 = *(const v8ss*)&Y1[(size_t)(m0 + 16 + cl) * 512 + ko];
    v8ss b0 = *(const v8ss*)&WtFC[(size_t)(n0 + cl) * 512 + ko];
    v8ss b1 = *(const v8ss*)&WtFC[(size_t)(n0 + 16 + cl) * 512 + ko];
    acc[0][0] = MFMA16(a0, b0, acc[0][0]);
    acc[0][1] = MFMA16(a0, b1, acc[0][1]);
    acc[1][0] = MFMA16(a1, b0, acc[1][0]);
    acc[1][1] = MFMA16(a1, b1, acc[1][1]);
  }
#pragma unroll
  for (int mi = 0; mi < 2; ++mi)
#pragma unroll
    for (int ni = 0; ni < 2; ++ni) {
      int col = n0 + ni * 16 + cl;
      float bias = fcb[col];
#pragma unroll
      for (int r = 0; r < 4; ++r)
        lout[(mi * 16 + kg * 4 + r) * 128 + col] = acc[mi][ni][r] + bias;
    }
  __syncthreads();

  for (int rr = 0; rr < 8; ++rr) {
    int lr = w * 8 + rr;
    float a = lout[lr * 128 + l], b2 = lout[lr * 128 + 64 + l];
    float m = fmaxf(a, b2);
#pragma unroll
    for (int off = 32; off; off >>= 1) m = fmaxf(m, __shfl_xor(m, off));
    float s = __expf(a - m) + __expf(b2 - m);
#pragma unroll
    for (int off = 32; off; off >>= 1) s += __shfl_xor(s, off);
    float lse = m + logf(s);
    int mrow = m0 + lr, t = mrow >> 5, bb = mrow & 31;
    float* o = &out[((size_t)bb * SS + t) * 128];
    o[l] = a - lse;
    o[l + 64] = b2 - lse;
  }
}

// ---------------------------------------------------------------------------
extern "C" void kernel_launch(void* const* d_in, const int* in_sizes, int n_in,
                              void* d_out, int out_size, void* d_ws, size_t ws_size,
                              hipStream_t stream) {
  (void)in_sizes; (void)n_in; (void)out_size; (void)ws_size;
  const int*   tokens = (const int*)d_in[0];
  const float* emb    = (const float*)d_in[1];
  const float* l0Wz = (const float*)d_in[2];  const float* l0bz = (const float*)d_in[3];
  const float* l0Wr = (const float*)d_in[4];  const float* l0br = (const float*)d_in[5];
  const float* l0Wn = (const float*)d_in[6];  const float* l0bn = (const float*)d_in[7];
  const float* l1Wz = (const float*)d_in[8];  const float* l1bz = (const float*)d_in[9];
  const float* l1Wr = (const float*)d_in[10]; const float* l1br = (const float*)d_in[11];
  const float* l1Wn = (const float*)d_in[12]; const float* l1bn = (const float*)d_in[13];
  const float* fcW  = (const float*)d_in[14]; const float* fcb  = (const float*)d_in[15];

  char* ws = (char*)d_ws;
  unsigned short* hx0  = (unsigned short*)(ws + O_HX0);
  unsigned short* hx1  = (unsigned short*)(ws + O_HX1);
  unsigned short* rhx0 = (unsigned short*)(ws + O_RHX0);
  unsigned short* rhx1 = (unsigned short*)(ws + O_RHX1);
  unsigned short* Wt0x = (unsigned short*)(ws + O_WT0X);
  unsigned short* Wt0h = (unsigned short*)(ws + O_WT0H);
  unsigned short* Wt1x = (unsigned short*)(ws + O_WT1X);
  unsigned short* Wt1h = (unsigned short*)(ws + O_WT1H);
  unsigned short* WtFC = (unsigned short*)(ws + O_WTFC);
  unsigned short* Xemb = (unsigned short*)(ws + O_XEMB);

  // h slabs: slot 0 = zeros (h0), slots 1..512 = sentinel; rhx all sentinel
  hipMemsetAsync(hx0, 0x00, 32768, stream);
  hipMemsetAsync((char*)hx0 + 32768, 0x80, (size_t)SS * 32768, stream);
  hipMemsetAsync(hx1, 0x00, 32768, stream);
  hipMemsetAsync((char*)hx1 + 32768, 0x80, (size_t)SS * 32768, stream);
  hipMemsetAsync(rhx0, 0x80, (size_t)SS * 32768, stream);
  hipMemsetAsync(rhx1, 0x80, (size_t)SS * 32768, stream);

  prep_kernel<<<4096, 256, 0, stream>>>(l0Wz, l0Wr, l0Wn, l1Wz, l1Wr, l1Wn, fcW,
                                        Wt0x, Wt0h, Wt1x, Wt1h, WtFC);
  embed_kernel<<<MROWS, 256, 0, stream>>>(tokens, emb, Xemb);

  gru_fused<<<256, 256, 0, stream>>>(Wt0h, Wt1h, Wt0x, Wt1x, Xemb,
                                     hx0, rhx0, hx1, rhx1,
                                     l0bz, l0br, l0bn, l1bz, l1br, l1bn);

  fc_lsm_kernel<<<512, 256, 0, stream>>>(hx1 + SLAB, WtFC, fcb, (float*)d_out);
}